// Round 1
// baseline (2156.108 us; speedup 1.0000x reference)
//
#include <hip/hip_runtime.h>
#include <cmath>

// Problem dims (fixed by setup_inputs)
#define T_    4
#define B_    64
#define N_    196
#define P_    768
#define D_    256
#define BN_   (B_*N_)          // 12544
#define M_    (T_*BN_)         // 50176
#define SITES (BN_*D_)         // 3211264

#define TILE  64
#define TK    16
#define MBLKS (M_/TILE)        // 784
#define NBLKS (D_/TILE)        // 4

// Packed f32 pair type + packed IEEE ops (two independent correctly-rounded
// f32 ops per instruction — NOT fused, so rounding is bit-identical to the
// scalar __fmul_rn/__fadd_rn sequence).
typedef __attribute__((ext_vector_type(2))) float f32x2;

__device__ __forceinline__ f32x2 pk_mul(f32x2 a, f32x2 b) {
    f32x2 d;
    asm("v_pk_mul_f32 %0, %1, %2" : "=v"(d) : "v"(a), "v"(b));
    return d;
}
__device__ __forceinline__ f32x2 pk_add(f32x2 a, f32x2 b) {
    f32x2 d;
    asm("v_pk_add_f32 %0, %1, %2" : "=v"(d) : "v"(a), "v"(b));
    return d;
}

// ---------------------------------------------------------------------------
// Kernel 1: numpy c_einsum f32 emulation, packed-f32 version.
// Per output element: 4 SSE lanes; lane j = sequential f32 sum over p≡j mod 4
// of fl32(x*w) (separate mul/add roundings, no FMA). Final combine
// (l0+l1)+(l2+l3). k-steps are processed in adjacent pairs (2kp, 2kp+1) so
// SSE lanes (0,1) / (2,3) live in one f32x2 accumulator and each mul/add is
// one v_pk_*_f32. Per-lane visit order over p is unchanged (p += 4), so the
// rounding sequence is bit-identical to the scalar emulation.
// LDS stores k-pair-interleaved tiles: As2[kp][m] = (x[m][k0+2kp], x[m][k0+2kp+1]).
// h written into d_out scratch, layout [m][d].
// ---------------------------------------------------------------------------
extern "C" __global__ __launch_bounds__(256)
void gemm_f32emu(const float* __restrict__ x, const float* __restrict__ w,
                 float* __restrict__ h) {
    __shared__ __align__(16) f32x2 As2[TK/2][66];   // stride 66: kills 4-way write conflicts
    __shared__ __align__(16) f32x2 Bs2[TK/2][66];

    const int tid  = threadIdx.x;
    const int tx   = tid & 15;       // d-group
    const int ty   = tid >> 4;       // m-group
    const int m0   = blockIdx.x * TILE;
    const int d0   = blockIdx.y * TILE;
    const int lrow = tid >> 2;       // 0..63: row within tile being staged
    const int kq   = tid & 3;        // which 4-k group this thread stages
    const int lk   = kq * 4;

    f32x2 acc[4][4][2];              // [i][j][lane-pair]: [0]=(l0,l1), [1]=(l2,l3)
#pragma unroll
    for (int i = 0; i < 4; ++i)
#pragma unroll
        for (int j = 0; j < 4; ++j)
#pragma unroll
            for (int p = 0; p < 2; ++p) acc[i][j][p] = f32x2{0.0f, 0.0f};

    for (int k0 = 0; k0 < P_; k0 += TK) {
        const float4 av = *(const float4*)(x + (size_t)(m0 + lrow) * P_ + k0 + lk);
        const float4 bv = *(const float4*)(w + (size_t)(d0 + lrow) * P_ + k0 + lk);
        As2[kq * 2 + 0][lrow] = f32x2{av.x, av.y};
        As2[kq * 2 + 1][lrow] = f32x2{av.z, av.w};
        Bs2[kq * 2 + 0][lrow] = f32x2{bv.x, bv.y};
        Bs2[kq * 2 + 1][lrow] = f32x2{bv.z, bv.w};
        __syncthreads();
#pragma unroll
        for (int kp = 0; kp < TK / 2; ++kp) {
            const int pi = kp & 1;   // kp even -> SSE lanes (0,1); odd -> (2,3)
            f32x2 a2[4], b2[4];
#pragma unroll
            for (int i = 0; i < 4; ++i) a2[i] = As2[kp][ty * 4 + i];
#pragma unroll
            for (int j = 0; j < 4; ++j) b2[j] = Bs2[kp][tx * 4 + j];
#pragma unroll
            for (int i = 0; i < 4; ++i)
#pragma unroll
                for (int j = 0; j < 4; ++j)
                    acc[i][j][pi] = pk_add(acc[i][j][pi], pk_mul(a2[i], b2[j]));
        }
        __syncthreads();
    }

#pragma unroll
    for (int i = 0; i < 4; ++i) {
        float4 o;
        float* hv = &o.x;
#pragma unroll
        for (int j = 0; j < 4; ++j) {
            const float l01 = __fadd_rn(acc[i][j][0].x, acc[i][j][0].y);
            const float l23 = __fadd_rn(acc[i][j][1].x, acc[i][j][1].y);
            hv[j] = __fadd_rn(l01, l23);
        }
        *(float4*)(h + (size_t)(m0 + ty * 4 + i) * D_ + d0 + tx * 4) = o;
    }
}

// ---------------------------------------------------------------------------
// Kernel 2: mean — numpy reduce on the transposed VIEW: per channel d,
// fully SEQUENTIAL f32 accumulation over m=0..M-1, then f32 divide.
// 16 blocks x 64 threads; lanes 0..15 active (d = blk*16+lane).
// ---------------------------------------------------------------------------
extern "C" __global__ __launch_bounds__(64)
void mean_seq(const float* __restrict__ h, float* __restrict__ mean_) {
    const int lane = threadIdx.x;
    if (lane >= 16) return;
    const int d = blockIdx.x * 16 + lane;
    float acc = 0.0f;
    for (int m = 0; m < M_; ++m)
        acc = __fadd_rn(acc, h[(size_t)m * D_ + d]);
    mean_[d] = __fdiv_rn(acc, 50176.0f);
}

// ---------------------------------------------------------------------------
// Kernel 3: var — ((h-mean)**2) is a fresh CONTIGUOUS array; its mean is
// per (t,b): acc = fl32(acc + pairwise_f32(chunk of 196)). Chunk interior
// emulated in f64 (pairwise ~ f64), join rounding in f32 emulated exactly.
// inv = 1/sqrt(var+1e-5), all correctly-rounded f32 ops.
// One block (64 lanes) per channel d.
// ---------------------------------------------------------------------------
extern "C" __global__ __launch_bounds__(64)
void var_seq(const float* __restrict__ h, const float* __restrict__ mean_,
             float* __restrict__ inv_) {
    const int d    = blockIdx.x;
    const int lane = threadIdx.x;
    const float mn = mean_[d];
    float accf = 0.0f;
    for (int tb = 0; tb < T_ * B_; ++tb) {
        double part = 0.0;
        for (int n = lane; n < N_; n += 64) {
            const float hv = h[((size_t)tb * N_ + n) * D_ + d];
            const float t1 = __fsub_rn(hv, mn);
            const float sq = __fmul_rn(t1, t1);
            part += (double)sq;
        }
#pragma unroll
        for (int off = 32; off; off >>= 1) part += __shfl_down(part, off);
        const float chunk = (float)part;          // lane 0 holds true value
        accf = __fadd_rn(accf, chunk);
    }
    if (lane == 0) {
        const float var = __fdiv_rn(accf, 50176.0f);
        inv_[d] = __fdiv_rn(1.0f, __fsqrt_rn(__fadd_rn(var, 1e-5f)));
    }
}

// ---------------------------------------------------------------------------
// Kernel 4: BN-apply + LIF1 + tAPE + LIF2, exact numpy-f32 op order.
// pe: NEP-50 — np.log(10000.0) is a strong f64 scalar, so div/arg are f64;
// sin/cos in f64, rounded to f32 on assignment. Spike ties: >= (H(0)=1).
// In-place on d_out: each thread reads its own 4 h cells, then overwrites.
// ---------------------------------------------------------------------------
extern "C" __global__ __launch_bounds__(256)
void lif_final(float* __restrict__ out, const float* __restrict__ mean_,
               const float* __restrict__ inv_, const float* __restrict__ gamma,
               const float* __restrict__ beta) {
    const int idx = blockIdx.x * 256 + threadIdx.x;   // (bn, d)
    const int d = idx & (D_ - 1);
    const int n = (idx >> 8) % N_;

    const float mn = mean_[d];
    const float iv = inv_[d];
    const float g  = gamma[d];
    const float b  = beta[d];

    const double dv  = exp((double)(d & ~1) * (-9.210340371976184 / 256.0));
    const double arg = ((double)n * dv) * (256.0 / 196.0);
    const float  pe  = (d & 1) ? (float)cos(arg) : (float)sin(arg);

    float hv[4];
#pragma unroll
    for (int t = 0; t < T_; ++t) hv[t] = out[(size_t)t * SITES + idx];

    float v1 = 0.0f, v2 = 0.0f, s2v[4];
#pragma unroll
    for (int t = 0; t < T_; ++t) {
        const float t1 = __fsub_rn(hv[t], mn);
        const float u  = __fmul_rn(t1, iv);
        const float hb = __fadd_rn(__fmul_rn(u, g), b);
        v1 = __fadd_rn(v1, __fmul_rn(__fsub_rn(hb, v1), 0.5f));
        const float s1 = (v1 >= 0.5f) ? 1.0f : 0.0f;
        v1 = __fmul_rn(v1, __fsub_rn(1.0f, s1));
        const float y = __fadd_rn(s1, pe);
        v2 = __fadd_rn(v2, __fmul_rn(__fsub_rn(y, v2), 0.5f));
        const float s2 = (v2 >= 0.5f) ? 1.0f : 0.0f;
        v2 = __fmul_rn(v2, __fsub_rn(1.0f, s2));
        s2v[t] = s2;
    }
#pragma unroll
    for (int t = 0; t < T_; ++t) out[(size_t)t * SITES + idx] = s2v[t];
}

extern "C" void kernel_launch(void* const* d_in, const int* in_sizes, int n_in,
                              void* d_out, int out_size, void* d_ws, size_t ws_size,
                              hipStream_t stream) {
    const float* x     = (const float*)d_in[0];
    const float* w     = (const float*)d_in[1];
    const float* gamma = (const float*)d_in[2];
    const float* beta  = (const float*)d_in[3];
    float* out = (float*)d_out;

    float* mean_ = (float*)d_ws;         // 256 floats
    float* inv_  = mean_ + D_;           // 256 floats

    gemm_f32emu<<<dim3(MBLKS, NBLKS), 256, 0, stream>>>(x, w, out);
    mean_seq<<<16, 64, 0, stream>>>(out, mean_);
    var_seq<<<D_, 64, 0, stream>>>(out, mean_, inv_);
    lif_final<<<SITES / 256, 256, 0, stream>>>(out, mean_, inv_, gamma, beta);
}

// Round 2
// 1324.382 us; speedup vs baseline: 1.6280x; 1.6280x over previous
//
#include <hip/hip_runtime.h>
#include <cmath>

// Problem dims (fixed by setup_inputs)
#define T_    4
#define B_    64
#define N_    196
#define P_    768
#define D_    256
#define BN_   (B_*N_)          // 12544
#define M_    (T_*BN_)         // 50176
#define SITES (BN_*D_)         // 3211264

#define TILE  64
#define TK    16
#define MBLKS (M_/TILE)        // 784
#define NBLKS (D_/TILE)        // 4

// Packed f32 pair type + packed IEEE ops (two independent correctly-rounded
// f32 ops per instruction — NOT fused, so rounding is bit-identical to the
// scalar __fmul_rn/__fadd_rn sequence).
typedef __attribute__((ext_vector_type(2))) float f32x2;

__device__ __forceinline__ f32x2 pk_mul(f32x2 a, f32x2 b) {
    f32x2 d;
    asm("v_pk_mul_f32 %0, %1, %2" : "=v"(d) : "v"(a), "v"(b));
    return d;
}
__device__ __forceinline__ f32x2 pk_add(f32x2 a, f32x2 b) {
    f32x2 d;
    asm("v_pk_add_f32 %0, %1, %2" : "=v"(d) : "v"(a), "v"(b));
    return d;
}

// ---------------------------------------------------------------------------
// Kernel 1: numpy c_einsum f32 emulation, packed-f32 version.
// Per output element: 4 SSE lanes; lane j = sequential f32 sum over p≡j mod 4
// of fl32(x*w) (separate mul/add roundings, no FMA). Final combine
// (l0+l1)+(l2+l3). k-steps processed in adjacent pairs so SSE lanes (0,1) /
// (2,3) live in one f32x2 accumulator; per-lane rounding sequence unchanged.
// h written into d_out scratch, layout [m][d].
// ---------------------------------------------------------------------------
extern "C" __global__ __launch_bounds__(256)
void gemm_f32emu(const float* __restrict__ x, const float* __restrict__ w,
                 float* __restrict__ h) {
    __shared__ __align__(16) f32x2 As2[TK/2][66];
    __shared__ __align__(16) f32x2 Bs2[TK/2][66];

    const int tid  = threadIdx.x;
    const int tx   = tid & 15;       // d-group
    const int ty   = tid >> 4;       // m-group
    const int m0   = blockIdx.x * TILE;
    const int d0   = blockIdx.y * TILE;
    const int lrow = tid >> 2;       // 0..63: row within tile being staged
    const int kq   = tid & 3;        // which 4-k group this thread stages
    const int lk   = kq * 4;

    f32x2 acc[4][4][2];              // [i][j][lane-pair]: [0]=(l0,l1), [1]=(l2,l3)
#pragma unroll
    for (int i = 0; i < 4; ++i)
#pragma unroll
        for (int j = 0; j < 4; ++j)
#pragma unroll
            for (int p = 0; p < 2; ++p) acc[i][j][p] = f32x2{0.0f, 0.0f};

    for (int k0 = 0; k0 < P_; k0 += TK) {
        const float4 av = *(const float4*)(x + (size_t)(m0 + lrow) * P_ + k0 + lk);
        const float4 bv = *(const float4*)(w + (size_t)(d0 + lrow) * P_ + k0 + lk);
        As2[kq * 2 + 0][lrow] = f32x2{av.x, av.y};
        As2[kq * 2 + 1][lrow] = f32x2{av.z, av.w};
        Bs2[kq * 2 + 0][lrow] = f32x2{bv.x, bv.y};
        Bs2[kq * 2 + 1][lrow] = f32x2{bv.z, bv.w};
        __syncthreads();
#pragma unroll
        for (int kp = 0; kp < TK / 2; ++kp) {
            const int pi = kp & 1;   // kp even -> SSE lanes (0,1); odd -> (2,3)
            f32x2 a2[4], b2[4];
#pragma unroll
            for (int i = 0; i < 4; ++i) a2[i] = As2[kp][ty * 4 + i];
#pragma unroll
            for (int j = 0; j < 4; ++j) b2[j] = Bs2[kp][tx * 4 + j];
#pragma unroll
            for (int i = 0; i < 4; ++i)
#pragma unroll
                for (int j = 0; j < 4; ++j)
                    acc[i][j][pi] = pk_add(acc[i][j][pi], pk_mul(a2[i], b2[j]));
        }
        __syncthreads();
    }

#pragma unroll
    for (int i = 0; i < 4; ++i) {
        float4 o;
        float* hv = &o.x;
#pragma unroll
        for (int j = 0; j < 4; ++j) {
            const float l01 = __fadd_rn(acc[i][j][0].x, acc[i][j][0].y);
            const float l23 = __fadd_rn(acc[i][j][1].x, acc[i][j][1].y);
            hv[j] = __fadd_rn(l01, l23);
        }
        *(float4*)(h + (size_t)(m0 + ty * 4 + i) * D_ + d0 + tx * 4) = o;
    }
}

// ---------------------------------------------------------------------------
// Kernel 2: mean — numpy reduce on the transposed VIEW: per channel d,
// fully SEQUENTIAL f32 accumulation over m=0..M-1 (exact rounding order),
// then f32 divide.
// NEW STRUCTURE: 16 blocks x 256 threads; each block owns 16 channels.
// Double-buffered LDS staging: all 256 threads cooperatively load a
// [256 m-rows x 16 ch] chunk (64B contiguous per thread -> full line use)
// while lanes 0..15 run the dependent add chain on the PREVIOUS chunk from
// LDS. Chain floor: 50176 dependent v_add_f32 @ ~4cyc ~= 84 us (vs 1177 us
// when each add stalled on a global load).
// ---------------------------------------------------------------------------
#define MCH  256      // m-rows per chunk
#define DCH  16       // channels per block
#define PADW 20       // row stride in LDS (pad 16->20 floats, keeps 16B align)
#define NCHK (M_/MCH) // 196

extern "C" __global__ __launch_bounds__(256)
void mean_seq(const float* __restrict__ h, float* __restrict__ mean_) {
    __shared__ __align__(16) float buf[2][MCH][PADW];   // 40 KB
    const int tid = threadIdx.x;
    const int d0  = blockIdx.x * DCH;

    // preload chunk 0: thread t stages row t (16 floats = 64B contiguous)
    {
        const float* rp = h + (size_t)tid * D_ + d0;
        const float4 v0 = *(const float4*)(rp + 0);
        const float4 v1 = *(const float4*)(rp + 4);
        const float4 v2 = *(const float4*)(rp + 8);
        const float4 v3 = *(const float4*)(rp + 12);
        *(float4*)&buf[0][tid][0]  = v0;
        *(float4*)&buf[0][tid][4]  = v1;
        *(float4*)&buf[0][tid][8]  = v2;
        *(float4*)&buf[0][tid][12] = v3;
    }
    __syncthreads();

    float acc = 0.0f;
    for (int c = 0; c < NCHK; ++c) {
        const int cb = c & 1;
        const bool have = (c + 1 < NCHK);
        float4 v0, v1, v2, v3;
        if (have) {   // issue next-chunk loads; latency hides under the chain
            const float* rp = h + ((size_t)(c + 1) * MCH + tid) * D_ + d0;
            v0 = *(const float4*)(rp + 0);
            v1 = *(const float4*)(rp + 4);
            v2 = *(const float4*)(rp + 8);
            v3 = *(const float4*)(rp + 12);
        }
        if (tid < DCH) {   // the sequential chain, exact m order
#pragma unroll 16
            for (int m = 0; m < MCH; ++m)
                acc = __fadd_rn(acc, buf[cb][m][tid]);
        }
        if (have) {
            *(float4*)&buf[cb ^ 1][tid][0]  = v0;
            *(float4*)&buf[cb ^ 1][tid][4]  = v1;
            *(float4*)&buf[cb ^ 1][tid][8]  = v2;
            *(float4*)&buf[cb ^ 1][tid][12] = v3;
        }
        __syncthreads();
    }
    if (tid < DCH) mean_[d0 + tid] = __fdiv_rn(acc, 50176.0f);
}

// ---------------------------------------------------------------------------
// Kernel 3: var — ((h-mean)**2) is a fresh CONTIGUOUS array; its mean is
// per (t,b): acc = fl32(acc + pairwise_f32(chunk of 196)). Chunk interior
// emulated in f64 (pairwise ~ f64), join rounding in f32 emulated exactly.
// inv = 1/sqrt(var+1e-5), all correctly-rounded f32 ops.
// One block (64 lanes) per channel d.
// ---------------------------------------------------------------------------
extern "C" __global__ __launch_bounds__(64)
void var_seq(const float* __restrict__ h, const float* __restrict__ mean_,
             float* __restrict__ inv_) {
    const int d    = blockIdx.x;
    const int lane = threadIdx.x;
    const float mn = mean_[d];
    float accf = 0.0f;
    for (int tb = 0; tb < T_ * B_; ++tb) {
        double part = 0.0;
        for (int n = lane; n < N_; n += 64) {
            const float hv = h[((size_t)tb * N_ + n) * D_ + d];
            const float t1 = __fsub_rn(hv, mn);
            const float sq = __fmul_rn(t1, t1);
            part += (double)sq;
        }
#pragma unroll
        for (int off = 32; off; off >>= 1) part += __shfl_down(part, off);
        const float chunk = (float)part;          // lane 0 holds true value
        accf = __fadd_rn(accf, chunk);
    }
    if (lane == 0) {
        const float var = __fdiv_rn(accf, 50176.0f);
        inv_[d] = __fdiv_rn(1.0f, __fsqrt_rn(__fadd_rn(var, 1e-5f)));
    }
}

// ---------------------------------------------------------------------------
// Kernel 3.5: pe table — identical f64 expressions as the inline path (same
// HW ops -> identical bits), computed once per (n,d) instead of per (t,b,n,d).
// ---------------------------------------------------------------------------
extern "C" __global__ __launch_bounds__(256)
void pe_build(float* __restrict__ pe_) {
    const int d = threadIdx.x;          // 0..255
    const int n = blockIdx.x;           // 0..195
    const double dv  = exp((double)(d & ~1) * (-9.210340371976184 / 256.0));
    const double arg = ((double)n * dv) * (256.0 / 196.0);
    pe_[(size_t)n * D_ + d] = (d & 1) ? (float)cos(arg) : (float)sin(arg);
}

// ---------------------------------------------------------------------------
// Kernel 4: BN-apply + LIF1 + tAPE + LIF2, exact numpy-f32 op order.
// pe from table if available (bit-identical), else inline f64 path.
// In-place on d_out: each thread reads its own 4 h cells, then overwrites.
// ---------------------------------------------------------------------------
extern "C" __global__ __launch_bounds__(256)
void lif_final(float* __restrict__ out, const float* __restrict__ mean_,
               const float* __restrict__ inv_, const float* __restrict__ gamma,
               const float* __restrict__ beta, const float* __restrict__ pe_tab) {
    const int idx = blockIdx.x * 256 + threadIdx.x;   // (bn, d)
    const int d = idx & (D_ - 1);
    const int n = (idx >> 8) % N_;

    const float mn = mean_[d];
    const float iv = inv_[d];
    const float g  = gamma[d];
    const float b  = beta[d];

    float pe;
    if (pe_tab) {
        pe = pe_tab[(size_t)n * D_ + d];
    } else {
        const double dv  = exp((double)(d & ~1) * (-9.210340371976184 / 256.0));
        const double arg = ((double)n * dv) * (256.0 / 196.0);
        pe = (d & 1) ? (float)cos(arg) : (float)sin(arg);
    }

    float hv[4];
#pragma unroll
    for (int t = 0; t < T_; ++t) hv[t] = out[(size_t)t * SITES + idx];

    float v1 = 0.0f, v2 = 0.0f, s2v[4];
#pragma unroll
    for (int t = 0; t < T_; ++t) {
        const float t1 = __fsub_rn(hv[t], mn);
        const float u  = __fmul_rn(t1, iv);
        const float hb = __fadd_rn(__fmul_rn(u, g), b);
        v1 = __fadd_rn(v1, __fmul_rn(__fsub_rn(hb, v1), 0.5f));
        const float s1 = (v1 >= 0.5f) ? 1.0f : 0.0f;
        v1 = __fmul_rn(v1, __fsub_rn(1.0f, s1));
        const float y = __fadd_rn(s1, pe);
        v2 = __fadd_rn(v2, __fmul_rn(__fsub_rn(y, v2), 0.5f));
        const float s2 = (v2 >= 0.5f) ? 1.0f : 0.0f;
        v2 = __fmul_rn(v2, __fsub_rn(1.0f, s2));
        s2v[t] = s2;
    }
#pragma unroll
    for (int t = 0; t < T_; ++t) out[(size_t)t * SITES + idx] = s2v[t];
}

extern "C" void kernel_launch(void* const* d_in, const int* in_sizes, int n_in,
                              void* d_out, int out_size, void* d_ws, size_t ws_size,
                              hipStream_t stream) {
    const float* x     = (const float*)d_in[0];
    const float* w     = (const float*)d_in[1];
    const float* gamma = (const float*)d_in[2];
    const float* beta  = (const float*)d_in[3];
    float* out = (float*)d_out;

    float* mean_ = (float*)d_ws;         // 256 floats
    float* inv_  = mean_ + D_;           // 256 floats
    float* pe_   = inv_  + D_;           // 196*256 floats (if ws allows)
    const bool use_pe = ws_size >= (size_t)(2 * D_ + N_ * D_) * sizeof(float);

    gemm_f32emu<<<dim3(MBLKS, NBLKS), 256, 0, stream>>>(x, w, out);
    mean_seq<<<16, 256, 0, stream>>>(out, mean_);
    var_seq<<<D_, 64, 0, stream>>>(out, mean_, inv_);
    if (use_pe) pe_build<<<N_, 256, 0, stream>>>(pe_);
    lif_final<<<SITES / 256, 256, 0, stream>>>(out, mean_, inv_, gamma, beta,
                                               use_pe ? pe_ : nullptr);
}

// Round 3
// 957.799 us; speedup vs baseline: 2.2511x; 1.3827x over previous
//
#include <hip/hip_runtime.h>
#include <cmath>

// Problem dims (fixed by setup_inputs)
#define T_    4
#define B_    64
#define N_    196
#define P_    768
#define D_    256
#define BN_   (B_*N_)          // 12544
#define M_    (T_*BN_)         // 50176
#define SITES (BN_*D_)         // 3211264

#define TILE  64
#define TK    16
#define MBLKS (M_/TILE)        // 784
#define NBLKS (D_/TILE)        // 4
#define LSTR  70               // LDS row stride in f32x2 (560B: rows spread banks, fits swizzle max 69)

typedef __attribute__((ext_vector_type(2))) float f32x2;

// ---------------------------------------------------------------------------
// Kernel 1: numpy c_einsum f32 emulation, packed-f32 via PLAIN operators.
// fp contract(off) => fmul<2xf32> + fadd<2xf32> lower to v_pk_mul_f32 /
// v_pk_add_f32 (two independent correctly-rounded IEEE ops, no FMA fusion)
// with native regalloc (no asm-forced copies).
// SSE-lane emulation: lane j = sequential f32 sum over p≡j mod 4; pairs
// (0,1)/(2,3) live in one f32x2 accumulator; per-lane rounding order exact.
// LDS index swizzle fsw(i) = i + 2*((i>>4)&3): B-fragment reads go from
// 4-way bank alias (tx*32 bytes mod 128) to <=2-way (free); preserves
// 4-element contiguity (b128 merges) since blocks of 4 never cross a
// 16-element boundary.
// XCD swizzle: bid%8 = XCD; each XCD owns 98 consecutive m-tiles x all 4
// d-tiles, so the 4 blocks sharing an x-panel share one L2.
// ---------------------------------------------------------------------------
extern "C" __global__ __launch_bounds__(256)
void gemm_f32emu(const float* __restrict__ x, const float* __restrict__ w,
                 float* __restrict__ h) {
#pragma clang fp contract(off)
    __shared__ __align__(16) f32x2 As2[TK/2][LSTR];
    __shared__ __align__(16) f32x2 Bs2[TK/2][LSTR];

    const int tid  = threadIdx.x;
    const int tx   = tid & 15;       // d-group
    const int ty   = tid >> 4;       // m-group
    const int bid  = blockIdx.x;     // 0..3135
    const int xcd  = bid & 7;
    const int lin  = bid >> 3;       // 0..391
    const int m0   = (xcd * 98 + (lin >> 2)) * TILE;
    const int d0   = (lin & 3) * TILE;
    const int lrow = tid >> 2;       // 0..63: row staged by this thread
    const int kq   = tid & 3;        // 4-k group staged
    const int lk   = kq * 4;
    const int srow  = lrow + 2 * ((lrow >> 4) & 3);    // swizzled store idx
    const int abase = ty * 4 + 2 * ((ty >> 2) & 3);    // swizzled read base (A)
    const int bbase = tx * 4 + 2 * ((tx >> 2) & 3);    // swizzled read base (B)

    f32x2 acc[4][4][2];              // [i][j][pair]: [0]=(l0,l1), [1]=(l2,l3)
#pragma unroll
    for (int i = 0; i < 4; ++i)
#pragma unroll
        for (int j = 0; j < 4; ++j)
#pragma unroll
            for (int p = 0; p < 2; ++p) acc[i][j][p] = f32x2{0.0f, 0.0f};

    for (int k0 = 0; k0 < P_; k0 += TK) {
        const float4 av = *(const float4*)(x + (size_t)(m0 + lrow) * P_ + k0 + lk);
        const float4 bv = *(const float4*)(w + (size_t)(d0 + lrow) * P_ + k0 + lk);
        As2[kq * 2 + 0][srow] = f32x2{av.x, av.y};
        As2[kq * 2 + 1][srow] = f32x2{av.z, av.w};
        Bs2[kq * 2 + 0][srow] = f32x2{bv.x, bv.y};
        Bs2[kq * 2 + 1][srow] = f32x2{bv.z, bv.w};
        __syncthreads();
#pragma unroll
        for (int kp = 0; kp < TK / 2; ++kp) {
            const int pi = kp & 1;   // kp even -> SSE lanes (0,1); odd -> (2,3)
            const f32x2* Ar = As2[kp];
            const f32x2* Br = Bs2[kp];
            f32x2 a2[4], b2[4];
#pragma unroll
            for (int i = 0; i < 4; ++i) a2[i] = Ar[abase + i];
#pragma unroll
            for (int j = 0; j < 4; ++j) b2[j] = Br[bbase + j];
#pragma unroll
            for (int i = 0; i < 4; ++i)
#pragma unroll
                for (int j = 0; j < 4; ++j) {
                    const f32x2 p = a2[i] * b2[j];        // v_pk_mul_f32
                    acc[i][j][pi] = acc[i][j][pi] + p;    // v_pk_add_f32
                }
        }
        __syncthreads();
    }

#pragma unroll
    for (int i = 0; i < 4; ++i) {
        float4 o;
        float* hv = &o.x;
#pragma unroll
        for (int j = 0; j < 4; ++j) {
            const float l01 = __fadd_rn(acc[i][j][0].x, acc[i][j][0].y);
            const float l23 = __fadd_rn(acc[i][j][1].x, acc[i][j][1].y);
            hv[j] = __fadd_rn(l01, l23);
        }
        *(float4*)(h + (size_t)(m0 + ty * 4 + i) * D_ + d0 + tx * 4) = o;
    }
}

// ---------------------------------------------------------------------------
// Kernel 1.5: 64x64 tiled transpose h[m][d] -> hT[d][m] (bit-exact copy).
// Makes the per-channel sequential reductions contiguous/coalesced.
// ---------------------------------------------------------------------------
extern "C" __global__ __launch_bounds__(256)
void transpose_hT(const float* __restrict__ h, float* __restrict__ hT) {
    __shared__ float tile[64][65];
    const int tid = threadIdx.x;
    const int m0 = blockIdx.x * 64;
    const int d0 = blockIdx.y * 64;
    const int r  = tid >> 4;         // 0..15
    const int c4 = (tid & 15) * 4;
#pragma unroll
    for (int i = 0; i < 4; ++i) {
        const float4 v = *(const float4*)&h[(size_t)(m0 + r + i * 16) * D_ + d0 + c4];
        *(float4*)&tile[r + i * 16][c4] = v;
    }
    __syncthreads();
#pragma unroll
    for (int i = 0; i < 4; ++i) {
        const int dr = r + i * 16;   // d-local
        float4 o;
        o.x = tile[c4 + 0][dr];
        o.y = tile[c4 + 1][dr];
        o.z = tile[c4 + 2][dr];
        o.w = tile[c4 + 3][dr];
        *(float4*)&hT[(size_t)(d0 + dr) * M_ + m0 + c4] = o;
    }
}

// ---------------------------------------------------------------------------
// Kernel 2a (hT path): mean — per channel d, fully SEQUENTIAL f32 chain over
// m=0..M-1 (exact numpy order). One block per channel: 255 threads stage the
// contiguous column into double-buffered LDS while lane 0 runs the chain.
// Chain floor: 50176 dependent v_add_f32 (~84 us), staging fully hidden.
// ---------------------------------------------------------------------------
#define MCH2 7168                    // 7 chunks * 7168 = 50176
extern "C" __global__ __launch_bounds__(256)
void mean_hT(const float* __restrict__ hT, float* __restrict__ mean_) {
    __shared__ float buf[2][MCH2];   // 56 KB
    const int tid = threadIdx.x;
    const float* src = hT + (size_t)blockIdx.x * M_;

#pragma unroll
    for (int u = 0; u < 7; ++u)
        *(float4*)&buf[0][(u * 256 + tid) * 4] =
            *(const float4*)&src[(u * 256 + tid) * 4];
    __syncthreads();

    float acc = 0.0f;
    for (int c = 0; c < 7; ++c) {
        const int cb = c & 1;
        const bool have = (c + 1 < 7);
        float4 v[7];
        if (have) {
            const float* rp = src + (c + 1) * MCH2;
#pragma unroll
            for (int u = 0; u < 7; ++u)
                v[u] = *(const float4*)&rp[(u * 256 + tid) * 4];
        }
        if (tid == 0) {
            const float* bp = buf[cb];
#pragma unroll 16
            for (int m = 0; m < MCH2; ++m) acc = __fadd_rn(acc, bp[m]);
        }
        if (have) {
#pragma unroll
            for (int u = 0; u < 7; ++u)
                *(float4*)&buf[cb ^ 1][(u * 256 + tid) * 4] = v[u];
        }
        __syncthreads();
    }
    if (tid == 0) mean_[blockIdx.x] = __fdiv_rn(acc, 50176.0f);
}

// ---------------------------------------------------------------------------
// Kernel 3a (hT path): var — per (t,b) chunk: f64 interior with the EXACT
// same lane-strided partials + shuffle tree as before (bit-identical order),
// but tb's run 4-way wave-parallel with coalesced contiguous loads; the f32
// join chain (accf over tb=0..255) is replayed serially from LDS.
// ---------------------------------------------------------------------------
extern "C" __global__ __launch_bounds__(256)
void var_hT(const float* __restrict__ hT, const float* __restrict__ mean_,
            float* __restrict__ inv_) {
    __shared__ float chunks[256];
    const int d    = blockIdx.x;
    const int tid  = threadIdx.x;
    const int wv   = tid >> 6;       // 0..3
    const int lane = tid & 63;
    const float mn = mean_[d];
    const float* col = hT + (size_t)d * M_;

    for (int tb = wv; tb < T_ * B_; tb += 4) {
        double part = 0.0;
        for (int n = lane; n < N_; n += 64) {
            const float hv = col[tb * N_ + n];
            const float t1 = __fsub_rn(hv, mn);
            const float sq = __fmul_rn(t1, t1);
            part += (double)sq;
        }
#pragma unroll
        for (int off = 32; off; off >>= 1) part += __shfl_down(part, off);
        if (lane == 0) chunks[tb] = (float)part;
    }
    __syncthreads();
    if (tid == 0) {
        float accf = 0.0f;
        for (int tb = 0; tb < T_ * B_; ++tb) accf = __fadd_rn(accf, chunks[tb]);
        const float var = __fdiv_rn(accf, 50176.0f);
        inv_[d] = __fdiv_rn(1.0f, __fsqrt_rn(__fadd_rn(var, 1e-5f)));
    }
}

// ---------------------------------------------------------------------------
// Fallback kernels (small workspace): round-2 versions reading h[m][d].
// ---------------------------------------------------------------------------
#define MCH  256
#define DCH  16
#define PADW 20
#define NCHK (M_/MCH)

extern "C" __global__ __launch_bounds__(256)
void mean_seq(const float* __restrict__ h, float* __restrict__ mean_) {
    __shared__ __align__(16) float buf[2][MCH][PADW];
    const int tid = threadIdx.x;
    const int d0  = blockIdx.x * DCH;
    {
        const float* rp = h + (size_t)tid * D_ + d0;
        *(float4*)&buf[0][tid][0]  = *(const float4*)(rp + 0);
        *(float4*)&buf[0][tid][4]  = *(const float4*)(rp + 4);
        *(float4*)&buf[0][tid][8]  = *(const float4*)(rp + 8);
        *(float4*)&buf[0][tid][12] = *(const float4*)(rp + 12);
    }
    __syncthreads();
    float acc = 0.0f;
    for (int c = 0; c < NCHK; ++c) {
        const int cb = c & 1;
        const bool have = (c + 1 < NCHK);
        float4 v0, v1, v2, v3;
        if (have) {
            const float* rp = h + ((size_t)(c + 1) * MCH + tid) * D_ + d0;
            v0 = *(const float4*)(rp + 0);
            v1 = *(const float4*)(rp + 4);
            v2 = *(const float4*)(rp + 8);
            v3 = *(const float4*)(rp + 12);
        }
        if (tid < DCH) {
#pragma unroll 16
            for (int m = 0; m < MCH; ++m)
                acc = __fadd_rn(acc, buf[cb][m][tid]);
        }
        if (have) {
            *(float4*)&buf[cb ^ 1][tid][0]  = v0;
            *(float4*)&buf[cb ^ 1][tid][4]  = v1;
            *(float4*)&buf[cb ^ 1][tid][8]  = v2;
            *(float4*)&buf[cb ^ 1][tid][12] = v3;
        }
        __syncthreads();
    }
    if (tid < DCH) mean_[d0 + tid] = __fdiv_rn(acc, 50176.0f);
}

extern "C" __global__ __launch_bounds__(64)
void var_seq(const float* __restrict__ h, const float* __restrict__ mean_,
             float* __restrict__ inv_) {
    const int d    = blockIdx.x;
    const int lane = threadIdx.x;
    const float mn = mean_[d];
    float accf = 0.0f;
    for (int tb = 0; tb < T_ * B_; ++tb) {
        double part = 0.0;
        for (int n = lane; n < N_; n += 64) {
            const float hv = h[((size_t)tb * N_ + n) * D_ + d];
            const float t1 = __fsub_rn(hv, mn);
            const float sq = __fmul_rn(t1, t1);
            part += (double)sq;
        }
#pragma unroll
        for (int off = 32; off; off >>= 1) part += __shfl_down(part, off);
        accf = __fadd_rn(accf, (float)part);
    }
    if (lane == 0) {
        const float var = __fdiv_rn(accf, 50176.0f);
        inv_[d] = __fdiv_rn(1.0f, __fsqrt_rn(__fadd_rn(var, 1e-5f)));
    }
}

// ---------------------------------------------------------------------------
// Kernel 3.5: pe table — identical f64 expressions as the inline path.
// ---------------------------------------------------------------------------
extern "C" __global__ __launch_bounds__(256)
void pe_build(float* __restrict__ pe_) {
    const int d = threadIdx.x;
    const int n = blockIdx.x;
    const double dv  = exp((double)(d & ~1) * (-9.210340371976184 / 256.0));
    const double arg = ((double)n * dv) * (256.0 / 196.0);
    pe_[(size_t)n * D_ + d] = (d & 1) ? (float)cos(arg) : (float)sin(arg);
}

// ---------------------------------------------------------------------------
// Kernel 4: BN-apply + LIF1 + tAPE + LIF2, exact numpy-f32 op order.
// ---------------------------------------------------------------------------
extern "C" __global__ __launch_bounds__(256)
void lif_final(float* __restrict__ out, const float* __restrict__ mean_,
               const float* __restrict__ inv_, const float* __restrict__ gamma,
               const float* __restrict__ beta, const float* __restrict__ pe_tab) {
    const int idx = blockIdx.x * 256 + threadIdx.x;   // (bn, d)
    const int d = idx & (D_ - 1);
    const int n = (idx >> 8) % N_;

    const float mn = mean_[d];
    const float iv = inv_[d];
    const float g  = gamma[d];
    const float b  = beta[d];

    float pe;
    if (pe_tab) {
        pe = pe_tab[(size_t)n * D_ + d];
    } else {
        const double dv  = exp((double)(d & ~1) * (-9.210340371976184 / 256.0));
        const double arg = ((double)n * dv) * (256.0 / 196.0);
        pe = (d & 1) ? (float)cos(arg) : (float)sin(arg);
    }

    float hv[4];
#pragma unroll
    for (int t = 0; t < T_; ++t) hv[t] = out[(size_t)t * SITES + idx];

    float v1 = 0.0f, v2 = 0.0f, s2v[4];
#pragma unroll
    for (int t = 0; t < T_; ++t) {
        const float t1 = __fsub_rn(hv[t], mn);
        const float u  = __fmul_rn(t1, iv);
        const float hb = __fadd_rn(__fmul_rn(u, g), b);
        v1 = __fadd_rn(v1, __fmul_rn(__fsub_rn(hb, v1), 0.5f));
        const float s1 = (v1 >= 0.5f) ? 1.0f : 0.0f;
        v1 = __fmul_rn(v1, __fsub_rn(1.0f, s1));
        const float y = __fadd_rn(s1, pe);
        v2 = __fadd_rn(v2, __fmul_rn(__fsub_rn(y, v2), 0.5f));
        const float s2 = (v2 >= 0.5f) ? 1.0f : 0.0f;
        v2 = __fmul_rn(v2, __fsub_rn(1.0f, s2));
        s2v[t] = s2;
    }
#pragma unroll
    for (int t = 0; t < T_; ++t) out[(size_t)t * SITES + idx] = s2v[t];
}

extern "C" void kernel_launch(void* const* d_in, const int* in_sizes, int n_in,
                              void* d_out, int out_size, void* d_ws, size_t ws_size,
                              hipStream_t stream) {
    const float* x     = (const float*)d_in[0];
    const float* w     = (const float*)d_in[1];
    const float* gamma = (const float*)d_in[2];
    const float* beta  = (const float*)d_in[3];
    float* out = (float*)d_out;

    float* mean_ = (float*)d_ws;         // 256
    float* inv_  = mean_ + D_;           // 256
    float* pe_   = inv_  + D_;           // 196*256
    float* hT_   = pe_   + (size_t)N_ * D_;   // 50176*256 (51.4 MB)

    const size_t need_pe = (size_t)(2 * D_ + N_ * D_) * sizeof(float);
    const size_t need_hT = need_pe + (size_t)M_ * D_ * sizeof(float);
    const bool use_pe = ws_size >= need_pe;
    const bool use_hT = ws_size >= need_hT;

    gemm_f32emu<<<MBLKS * NBLKS, 256, 0, stream>>>(x, w, out);
    if (use_hT) {
        transpose_hT<<<dim3(MBLKS, NBLKS), 256, 0, stream>>>(out, hT_);
        mean_hT<<<D_, 256, 0, stream>>>(hT_, mean_);
        var_hT<<<D_, 256, 0, stream>>>(hT_, mean_, inv_);
    } else {
        mean_seq<<<16, 256, 0, stream>>>(out, mean_);
        var_seq<<<D_, 64, 0, stream>>>(out, mean_, inv_);
    }
    if (use_pe) pe_build<<<N_, 256, 0, stream>>>(pe_);
    lif_final<<<SITES / 256, 256, 0, stream>>>(out, mean_, inv_, gamma, beta,
                                               use_pe ? pe_ : nullptr);
}

// Round 4
// 906.448 us; speedup vs baseline: 2.3786x; 1.0567x over previous
//
#include <hip/hip_runtime.h>
#include <cmath>

// Problem dims (fixed by setup_inputs)
#define T_    4
#define B_    64
#define N_    196
#define P_    768
#define D_    256
#define BN_   (B_*N_)          // 12544
#define M_    (T_*BN_)         // 50176
#define SITES (BN_*D_)         // 3211264

#define TILE  64
#define TK    16
#define KITER (P_/TK)          // 48
#define MBLKS (M_/TILE)        // 784
#define NBLKS (D_/TILE)        // 4
#define LSTR  66               // LDS row stride in f32x2

typedef __attribute__((ext_vector_type(2))) float f32x2;

// pk mul+add with TIED accumulator: exactly 2 VALU instrs, no register
// copies. v_pk_* are two independent correctly-rounded IEEE f32 ops (no
// fusion) -> bit-identical to the scalar __fmul_rn/__fadd_rn sequence.
__device__ __forceinline__ void pk_fma(f32x2& acc, f32x2 a, f32x2 b) {
    f32x2 t;
    asm("v_pk_mul_f32 %1, %2, %3\n\t"
        "v_pk_add_f32 %0, %0, %1"
        : "+v"(acc), "=&v"(t) : "v"(a), "v"(b));
}

// ---------------------------------------------------------------------------
// Kernel 1: numpy c_einsum f32 emulation (SSE 4-lane semantics).
// lane j = sequential f32 sum over p≡j mod 4 of fl32(x*w); final combine
// (l0+l1)+(l2+l3). Lane pairs (0,1)/(2,3) in one f32x2 acc; per-lane
// rounding order exact. Double-buffered LDS: ONE barrier per k-step,
// next-tile global loads issued before compute (latency hidden).
// Epilogue writes BOTH h[m][d] (for lif_final) and hT[d][m] (for mean/var)
// from registers — kills the separate transpose kernel.
// XCD swizzle: bid%8 = XCD owns 98 consecutive m-tiles x all 4 d-tiles.
// ---------------------------------------------------------------------------
extern "C" __global__ __launch_bounds__(256)
void gemm_f32emu(const float* __restrict__ x, const float* __restrict__ w,
                 float* __restrict__ h, float* __restrict__ hT) {
    __shared__ __align__(16) f32x2 As2[2][TK/2][LSTR];
    __shared__ __align__(16) f32x2 Bs2[2][TK/2][LSTR];

    const int tid  = threadIdx.x;
    const int tx   = tid & 15;       // d-group
    const int ty   = tid >> 4;       // m-group
    const int bid  = blockIdx.x;     // 0..3135
    const int xcd  = bid & 7;
    const int lin  = bid >> 3;       // 0..391
    const int m0   = (xcd * 98 + (lin >> 2)) * TILE;
    const int d0   = (lin & 3) * TILE;
    const int lrow = tid >> 2;       // 0..63: row staged by this thread
    const int kq   = tid & 3;        // 4-k group staged
    const int lk   = kq * 4;

    const float* xp = x + (size_t)(m0 + lrow) * P_ + lk;
    const float* wp = w + (size_t)(d0 + lrow) * P_ + lk;

    f32x2 acc[4][4][2];              // [i][j][pair]: [0]=(l0,l1), [1]=(l2,l3)
#pragma unroll
    for (int i = 0; i < 4; ++i)
#pragma unroll
        for (int j = 0; j < 4; ++j)
#pragma unroll
            for (int p = 0; p < 2; ++p) acc[i][j][p] = f32x2{0.0f, 0.0f};

    // prologue: stage tile 0
    {
        const float4 av = *(const float4*)xp;
        const float4 bv = *(const float4*)wp;
        As2[0][kq * 2 + 0][lrow] = f32x2{av.x, av.y};
        As2[0][kq * 2 + 1][lrow] = f32x2{av.z, av.w};
        Bs2[0][kq * 2 + 0][lrow] = f32x2{bv.x, bv.y};
        Bs2[0][kq * 2 + 1][lrow] = f32x2{bv.z, bv.w};
    }

    int cur = 0;
    for (int k0 = 0; k0 < KITER; ++k0) {
        __syncthreads();             // buf[cur] ready; prev reads of cur^1 done
        float4 av, bv;
        const bool have = (k0 + 1 < KITER);
        if (have) {                  // issue next-tile loads; hide under compute
            av = *(const float4*)(xp + (k0 + 1) * TK);
            bv = *(const float4*)(wp + (k0 + 1) * TK);
        }
#pragma unroll
        for (int kp = 0; kp < TK / 2; ++kp) {
            const int pi = kp & 1;   // kp even -> SSE lanes (0,1); odd -> (2,3)
            const f32x2* Ar = As2[cur][kp];
            const f32x2* Br = Bs2[cur][kp];
            f32x2 a2[4], b2[4];
#pragma unroll
            for (int i = 0; i < 4; ++i) a2[i] = Ar[ty * 4 + i];
#pragma unroll
            for (int j = 0; j < 4; ++j) b2[j] = Br[tx * 4 + j];
#pragma unroll
            for (int i = 0; i < 4; ++i)
#pragma unroll
                for (int j = 0; j < 4; ++j)
                    pk_fma(acc[i][j][pi], a2[i], b2[j]);
        }
        if (have) {
            As2[cur ^ 1][kq * 2 + 0][lrow] = f32x2{av.x, av.y};
            As2[cur ^ 1][kq * 2 + 1][lrow] = f32x2{av.z, av.w};
            Bs2[cur ^ 1][kq * 2 + 0][lrow] = f32x2{bv.x, bv.y};
            Bs2[cur ^ 1][kq * 2 + 1][lrow] = f32x2{bv.z, bv.w};
        }
        cur ^= 1;
    }

    // epilogue: SSE lane combine, write h[m][d] and (optionally) hT[d][m]
    float res[4][4];
#pragma unroll
    for (int i = 0; i < 4; ++i)
#pragma unroll
        for (int j = 0; j < 4; ++j) {
            const float l01 = __fadd_rn(acc[i][j][0].x, acc[i][j][0].y);
            const float l23 = __fadd_rn(acc[i][j][1].x, acc[i][j][1].y);
            res[i][j] = __fadd_rn(l01, l23);
        }
#pragma unroll
    for (int i = 0; i < 4; ++i) {
        float4 o = {res[i][0], res[i][1], res[i][2], res[i][3]};
        *(float4*)(h + (size_t)(m0 + ty * 4 + i) * D_ + d0 + tx * 4) = o;
    }
    if (hT) {
#pragma unroll
        for (int j = 0; j < 4; ++j) {
            float4 o = {res[0][j], res[1][j], res[2][j], res[3][j]};
            *(float4*)(hT + (size_t)(d0 + tx * 4 + j) * M_ + m0 + ty * 4) = o;
        }
    }
}

// ---------------------------------------------------------------------------
// Kernel 2a (hT path): mean — per channel d, fully SEQUENTIAL f32 chain over
// m=0..M-1 (exact numpy order). One block per channel: threads stage the
// contiguous column into double-buffered LDS while lane 0 runs the chain.
// Chain floor: 50176 dependent v_add_f32 (~84 us), staging fully hidden.
// ---------------------------------------------------------------------------
#define MCH2 7168                    // 7 chunks * 7168 = 50176
extern "C" __global__ __launch_bounds__(256)
void mean_hT(const float* __restrict__ hT, float* __restrict__ mean_) {
    __shared__ float buf[2][MCH2];   // 56 KB
    const int tid = threadIdx.x;
    const float* src = hT + (size_t)blockIdx.x * M_;

#pragma unroll
    for (int u = 0; u < 7; ++u)
        *(float4*)&buf[0][(u * 256 + tid) * 4] =
            *(const float4*)&src[(u * 256 + tid) * 4];
    __syncthreads();

    float acc = 0.0f;
    for (int c = 0; c < 7; ++c) {
        const int cb = c & 1;
        const bool have = (c + 1 < 7);
        float4 v[7];
        if (have) {
            const float* rp = src + (c + 1) * MCH2;
#pragma unroll
            for (int u = 0; u < 7; ++u)
                v[u] = *(const float4*)&rp[(u * 256 + tid) * 4];
        }
        if (tid == 0) {
            const float2* bp2 = (const float2*)buf[cb];
#pragma unroll 8
            for (int m2 = 0; m2 < MCH2 / 2; ++m2) {
                const float2 vv = bp2[m2];
                acc = __fadd_rn(acc, vv.x);
                acc = __fadd_rn(acc, vv.y);
            }
        }
        if (have) {
#pragma unroll
            for (int u = 0; u < 7; ++u)
                *(float4*)&buf[cb ^ 1][(u * 256 + tid) * 4] = v[u];
        }
        __syncthreads();
    }
    if (tid == 0) mean_[blockIdx.x] = __fdiv_rn(acc, 50176.0f);
}

// ---------------------------------------------------------------------------
// Kernel 3a (hT path): var — per (t,b) chunk: f64 interior with the EXACT
// lane-strided partials + shuffle tree (bit-identical order); tb's run 4-way
// wave-parallel with coalesced loads; f32 join chain replayed serially.
// ---------------------------------------------------------------------------
extern "C" __global__ __launch_bounds__(256)
void var_hT(const float* __restrict__ hT, const float* __restrict__ mean_,
            float* __restrict__ inv_) {
    __shared__ float chunks[256];
    const int d    = blockIdx.x;
    const int tid  = threadIdx.x;
    const int wv   = tid >> 6;       // 0..3
    const int lane = tid & 63;
    const float mn = mean_[d];
    const float* col = hT + (size_t)d * M_;

    for (int tb = wv; tb < T_ * B_; tb += 4) {
        double part = 0.0;
        for (int n = lane; n < N_; n += 64) {
            const float hv = col[tb * N_ + n];
            const float t1 = __fsub_rn(hv, mn);
            const float sq = __fmul_rn(t1, t1);
            part += (double)sq;
        }
#pragma unroll
        for (int off = 32; off; off >>= 1) part += __shfl_down(part, off);
        if (lane == 0) chunks[tb] = (float)part;
    }
    __syncthreads();
    if (tid == 0) {
        float accf = 0.0f;
        for (int tb = 0; tb < T_ * B_; ++tb) accf = __fadd_rn(accf, chunks[tb]);
        const float var = __fdiv_rn(accf, 50176.0f);
        inv_[d] = __fdiv_rn(1.0f, __fsqrt_rn(__fadd_rn(var, 1e-5f)));
    }
}

// ---------------------------------------------------------------------------
// Fallback kernels (small workspace): read h[m][d] directly.
// ---------------------------------------------------------------------------
#define MCH  256
#define DCH  16
#define PADW 20
#define NCHK (M_/MCH)

extern "C" __global__ __launch_bounds__(256)
void mean_seq(const float* __restrict__ h, float* __restrict__ mean_) {
    __shared__ __align__(16) float buf[2][MCH][PADW];
    const int tid = threadIdx.x;
    const int d0  = blockIdx.x * DCH;
    {
        const float* rp = h + (size_t)tid * D_ + d0;
        *(float4*)&buf[0][tid][0]  = *(const float4*)(rp + 0);
        *(float4*)&buf[0][tid][4]  = *(const float4*)(rp + 4);
        *(float4*)&buf[0][tid][8]  = *(const float4*)(rp + 8);
        *(float4*)&buf[0][tid][12] = *(const float4*)(rp + 12);
    }
    __syncthreads();
    float acc = 0.0f;
    for (int c = 0; c < NCHK; ++c) {
        const int cb = c & 1;
        const bool have = (c + 1 < NCHK);
        float4 v0, v1, v2, v3;
        if (have) {
            const float* rp = h + ((size_t)(c + 1) * MCH + tid) * D_ + d0;
            v0 = *(const float4*)(rp + 0);
            v1 = *(const float4*)(rp + 4);
            v2 = *(const float4*)(rp + 8);
            v3 = *(const float4*)(rp + 12);
        }
        if (tid < DCH) {
#pragma unroll 16
            for (int m = 0; m < MCH; ++m)
                acc = __fadd_rn(acc, buf[cb][m][tid]);
        }
        if (have) {
            *(float4*)&buf[cb ^ 1][tid][0]  = v0;
            *(float4*)&buf[cb ^ 1][tid][4]  = v1;
            *(float4*)&buf[cb ^ 1][tid][8]  = v2;
            *(float4*)&buf[cb ^ 1][tid][12] = v3;
        }
        __syncthreads();
    }
    if (tid < DCH) mean_[d0 + tid] = __fdiv_rn(acc, 50176.0f);
}

extern "C" __global__ __launch_bounds__(64)
void var_seq(const float* __restrict__ h, const float* __restrict__ mean_,
             float* __restrict__ inv_) {
    const int d    = blockIdx.x;
    const int lane = threadIdx.x;
    const float mn = mean_[d];
    float accf = 0.0f;
    for (int tb = 0; tb < T_ * B_; ++tb) {
        double part = 0.0;
        for (int n = lane; n < N_; n += 64) {
            const float hv = h[((size_t)tb * N_ + n) * D_ + d];
            const float t1 = __fsub_rn(hv, mn);
            const float sq = __fmul_rn(t1, t1);
            part += (double)sq;
        }
#pragma unroll
        for (int off = 32; off; off >>= 1) part += __shfl_down(part, off);
        accf = __fadd_rn(accf, (float)part);
    }
    if (lane == 0) {
        const float var = __fdiv_rn(accf, 50176.0f);
        inv_[d] = __fdiv_rn(1.0f, __fsqrt_rn(__fadd_rn(var, 1e-5f)));
    }
}

// ---------------------------------------------------------------------------
// Kernel 3.5: pe table — identical f64 expressions as the inline path.
// ---------------------------------------------------------------------------
extern "C" __global__ __launch_bounds__(256)
void pe_build(float* __restrict__ pe_) {
    const int d = threadIdx.x;
    const int n = blockIdx.x;
    const double dv  = exp((double)(d & ~1) * (-9.210340371976184 / 256.0));
    const double arg = ((double)n * dv) * (256.0 / 196.0);
    pe_[(size_t)n * D_ + d] = (d & 1) ? (float)cos(arg) : (float)sin(arg);
}

// ---------------------------------------------------------------------------
// Kernel 4: BN-apply + LIF1 + tAPE + LIF2, exact numpy-f32 op order.
// ---------------------------------------------------------------------------
extern "C" __global__ __launch_bounds__(256)
void lif_final(float* __restrict__ out, const float* __restrict__ mean_,
               const float* __restrict__ inv_, const float* __restrict__ gamma,
               const float* __restrict__ beta, const float* __restrict__ pe_tab) {
    const int idx = blockIdx.x * 256 + threadIdx.x;   // (bn, d)
    const int d = idx & (D_ - 1);
    const int n = (idx >> 8) % N_;

    const float mn = mean_[d];
    const float iv = inv_[d];
    const float g  = gamma[d];
    const float b  = beta[d];

    float pe;
    if (pe_tab) {
        pe = pe_tab[(size_t)n * D_ + d];
    } else {
        const double dv  = exp((double)(d & ~1) * (-9.210340371976184 / 256.0));
        const double arg = ((double)n * dv) * (256.0 / 196.0);
        pe = (d & 1) ? (float)cos(arg) : (float)sin(arg);
    }

    float hv[4];
#pragma unroll
    for (int t = 0; t < T_; ++t) hv[t] = out[(size_t)t * SITES + idx];

    float v1 = 0.0f, v2 = 0.0f, s2v[4];
#pragma unroll
    for (int t = 0; t < T_; ++t) {
        const float t1 = __fsub_rn(hv[t], mn);
        const float u  = __fmul_rn(t1, iv);
        const float hb = __fadd_rn(__fmul_rn(u, g), b);
        v1 = __fadd_rn(v1, __fmul_rn(__fsub_rn(hb, v1), 0.5f));
        const float s1 = (v1 >= 0.5f) ? 1.0f : 0.0f;
        v1 = __fmul_rn(v1, __fsub_rn(1.0f, s1));
        const float y = __fadd_rn(s1, pe);
        v2 = __fadd_rn(v2, __fmul_rn(__fsub_rn(y, v2), 0.5f));
        const float s2 = (v2 >= 0.5f) ? 1.0f : 0.0f;
        v2 = __fmul_rn(v2, __fsub_rn(1.0f, s2));
        s2v[t] = s2;
    }
#pragma unroll
    for (int t = 0; t < T_; ++t) out[(size_t)t * SITES + idx] = s2v[t];
}

extern "C" void kernel_launch(void* const* d_in, const int* in_sizes, int n_in,
                              void* d_out, int out_size, void* d_ws, size_t ws_size,
                              hipStream_t stream) {
    const float* x     = (const float*)d_in[0];
    const float* w     = (const float*)d_in[1];
    const float* gamma = (const float*)d_in[2];
    const float* beta  = (const float*)d_in[3];
    float* out = (float*)d_out;

    float* mean_ = (float*)d_ws;              // 256
    float* inv_  = mean_ + D_;                // 256
    float* pe_   = inv_  + D_;                // 196*256
    float* hT_   = pe_   + (size_t)N_ * D_;   // 50176*256 (51.4 MB)

    const size_t need_pe = (size_t)(2 * D_ + N_ * D_) * sizeof(float);
    const size_t need_hT = need_pe + (size_t)M_ * D_ * sizeof(float);
    const bool use_pe = ws_size >= need_pe;
    const bool use_hT = ws_size >= need_hT;

    gemm_f32emu<<<MBLKS * NBLKS, 256, 0, stream>>>(x, w, out,
                                                   use_hT ? hT_ : nullptr);
    if (use_hT) {
        mean_hT<<<D_, 256, 0, stream>>>(hT_, mean_);
        var_hT<<<D_, 256, 0, stream>>>(hT_, mean_, inv_);
    } else {
        mean_seq<<<16, 256, 0, stream>>>(out, mean_);
        var_seq<<<D_, 64, 0, stream>>>(out, mean_, inv_);
    }
    if (use_pe) pe_build<<<N_, 256, 0, stream>>>(pe_);
    lif_final<<<SITES / 256, 256, 0, stream>>>(out, mean_, inv_, gamma, beta,
                                               use_pe ? pe_ : nullptr);
}

// Round 5
// 855.567 us; speedup vs baseline: 2.5201x; 1.0595x over previous
//
#include <hip/hip_runtime.h>
#include <cmath>

// Problem dims (fixed by setup_inputs)
#define T_    4
#define B_    64
#define N_    196
#define P_    768
#define D_    256
#define BN_   (B_*N_)          // 12544
#define M_    (T_*BN_)         // 50176
#define SITES (BN_*D_)         // 3211264

#define TILE  64
#define TK    16
#define KITER (P_/TK)          // 48
#define MBLKS (M_/TILE)        // 784
#define NBLKS (D_/TILE)        // 4
#define RLEN  98               // f32x2 per kp-row: 16 groups * 6 + 2; 784B -> rows shift banks by 4, b128-aligned

typedef __attribute__((ext_vector_type(2))) float f32x2;

// pk mul+add with TIED accumulator: exactly 2 VALU instrs, no register
// copies. v_pk_* are two independent correctly-rounded IEEE f32 ops (no
// fusion) -> bit-identical to the scalar __fmul_rn/__fadd_rn sequence.
__device__ __forceinline__ void pk_fma(f32x2& acc, f32x2 a, f32x2 b) {
    f32x2 t;
    asm("v_pk_mul_f32 %1, %2, %3\n\t"
        "v_pk_add_f32 %0, %0, %1"
        : "+v"(acc), "=&v"(t) : "v"(a), "v"(b));
}

// ---------------------------------------------------------------------------
// Kernel 1: numpy c_einsum f32 emulation (SSE 4-lane semantics).
// lane j = sequential f32 sum over p≡j mod 4 of fl32(x*w); final combine
// (l0+l1)+(l2+l3). Lane pairs (0,1)/(2,3) in one f32x2 acc; per-lane
// rounding order exact.
// LDS layout: rows stored in 4-element groups with stride 6 f32x2
// (off = (r>>2)*6 + (r&3)); row length 98 f32x2 (784B: rows shift banks by
// 4, group base 48B*g keeps 16B alignment). Fragment reads become two
// ds_read_b128 per side: A-read = 4 distinct addrs/wave (broadcast), B-read
// spreads 16 addrs across banks at <=2-way (free). Kills the 3.85e7
// bank-conflict plateau from the old 32B-stride b64 reads.
// Double-buffered LDS, one barrier per k-step, prefetch before compute.
// Epilogue writes h[m][d] and hT[d][m] from registers.
// XCD swizzle: bid%8 = XCD owns 98 consecutive m-tiles x all 4 d-tiles.
// ---------------------------------------------------------------------------
extern "C" __global__ __launch_bounds__(256)
void gemm_f32emu(const float* __restrict__ x, const float* __restrict__ w,
                 float* __restrict__ h, float* __restrict__ hT) {
    __shared__ __align__(16) f32x2 As2[2][TK/2][RLEN];   // 12.25 KB
    __shared__ __align__(16) f32x2 Bs2[2][TK/2][RLEN];   // 12.25 KB

    const int tid  = threadIdx.x;
    const int tx   = tid & 15;       // d-group
    const int ty   = tid >> 4;       // m-group
    const int bid  = blockIdx.x;     // 0..3135
    const int xcd  = bid & 7;
    const int lin  = bid >> 3;       // 0..391
    const int m0   = (xcd * 98 + (lin >> 2)) * TILE;
    const int d0   = (lin & 3) * TILE;
    const int lrow = tid >> 2;       // 0..63: row staged by this thread
    const int kq   = tid & 3;        // 4-k group staged
    const int lk   = kq * 4;
    const int woff = (lrow >> 2) * 6 + (lrow & 3);   // grouped-row store offset
    const int abase = ty * 6;        // read base (A), f32x2 units
    const int bbase = tx * 6;        // read base (B)

    const float* xp = x + (size_t)(m0 + lrow) * P_ + lk;
    const float* wp = w + (size_t)(d0 + lrow) * P_ + lk;

    f32x2 acc[4][4][2];              // [i][j][pair]: [0]=(l0,l1), [1]=(l2,l3)
#pragma unroll
    for (int i = 0; i < 4; ++i)
#pragma unroll
        for (int j = 0; j < 4; ++j)
#pragma unroll
            for (int p = 0; p < 2; ++p) acc[i][j][p] = f32x2{0.0f, 0.0f};

    // prologue: stage tile 0
    {
        const float4 av = *(const float4*)xp;
        const float4 bv = *(const float4*)wp;
        As2[0][kq * 2 + 0][woff] = f32x2{av.x, av.y};
        As2[0][kq * 2 + 1][woff] = f32x2{av.z, av.w};
        Bs2[0][kq * 2 + 0][woff] = f32x2{bv.x, bv.y};
        Bs2[0][kq * 2 + 1][woff] = f32x2{bv.z, bv.w};
    }

    int cur = 0;
    for (int k0 = 0; k0 < KITER; ++k0) {
        __syncthreads();             // buf[cur] ready; prev reads of cur^1 done
        float4 av, bv;
        const bool have = (k0 + 1 < KITER);
        if (have) {                  // issue next-tile loads; hide under compute
            av = *(const float4*)(xp + (k0 + 1) * TK);
            bv = *(const float4*)(wp + (k0 + 1) * TK);
        }
#pragma unroll
        for (int kp = 0; kp < TK / 2; ++kp) {
            const int pi = kp & 1;   // kp even -> SSE lanes (0,1); odd -> (2,3)
            const f32x2* Ar = As2[cur][kp];
            const f32x2* Br = Bs2[cur][kp];
            const float4 aa0 = *(const float4*)(Ar + abase);      // ds_read_b128
            const float4 aa1 = *(const float4*)(Ar + abase + 2);
            const float4 bb0 = *(const float4*)(Br + bbase);
            const float4 bb1 = *(const float4*)(Br + bbase + 2);
            f32x2 a2[4], b2[4];
            a2[0] = f32x2{aa0.x, aa0.y}; a2[1] = f32x2{aa0.z, aa0.w};
            a2[2] = f32x2{aa1.x, aa1.y}; a2[3] = f32x2{aa1.z, aa1.w};
            b2[0] = f32x2{bb0.x, bb0.y}; b2[1] = f32x2{bb0.z, bb0.w};
            b2[2] = f32x2{bb1.x, bb1.y}; b2[3] = f32x2{bb1.z, bb1.w};
#pragma unroll
            for (int i = 0; i < 4; ++i)
#pragma unroll
                for (int j = 0; j < 4; ++j)
                    pk_fma(acc[i][j][pi], a2[i], b2[j]);
        }
        if (have) {
            As2[cur ^ 1][kq * 2 + 0][woff] = f32x2{av.x, av.y};
            As2[cur ^ 1][kq * 2 + 1][woff] = f32x2{av.z, av.w};
            Bs2[cur ^ 1][kq * 2 + 0][woff] = f32x2{bv.x, bv.y};
            Bs2[cur ^ 1][kq * 2 + 1][woff] = f32x2{bv.z, bv.w};
        }
        cur ^= 1;
    }

    // epilogue: SSE lane combine, write h[m][d] and (optionally) hT[d][m]
    float res[4][4];
#pragma unroll
    for (int i = 0; i < 4; ++i)
#pragma unroll
        for (int j = 0; j < 4; ++j) {
            const float l01 = __fadd_rn(acc[i][j][0].x, acc[i][j][0].y);
            const float l23 = __fadd_rn(acc[i][j][1].x, acc[i][j][1].y);
            res[i][j] = __fadd_rn(l01, l23);
        }
#pragma unroll
    for (int i = 0; i < 4; ++i) {
        float4 o = {res[i][0], res[i][1], res[i][2], res[i][3]};
        *(float4*)(h + (size_t)(m0 + ty * 4 + i) * D_ + d0 + tx * 4) = o;
    }
    if (hT) {
#pragma unroll
        for (int j = 0; j < 4; ++j) {
            float4 o = {res[0][j], res[1][j], res[2][j], res[3][j]};
            *(float4*)(hT + (size_t)(d0 + tx * 4 + j) * M_ + m0 + ty * 4) = o;
        }
    }
}

// ---------------------------------------------------------------------------
// Kernel 2a (hT path): mean — per channel d, fully SEQUENTIAL f32 chain over
// m=0..M-1 (exact numpy order). One block per channel: threads stage the
// contiguous column into double-buffered LDS while lane 0 runs the chain.
// Chain uses REGISTER ping-pong: prefetch 32 floats (8x ds_read_b128) into
// p1 while the 32 dependent adds consume p0 — 128 cyc of adds covers the
// ~120 cyc LDS latency, so the chain runs at ~4.3 cyc/add (~95 us) instead
// of stalling on lgkmcnt(0) every 16 adds (~240 us).
// ---------------------------------------------------------------------------
#define MCH2 7168                    // 7 chunks * 7168 = 50176
#define GRP  224                     // 7168/32 float-groups per chunk
extern "C" __global__ __launch_bounds__(256)
void mean_hT(const float* __restrict__ hT, float* __restrict__ mean_) {
    __shared__ float buf[2][MCH2];   // 56 KB
    const int tid = threadIdx.x;
    const float* src = hT + (size_t)blockIdx.x * M_;

#pragma unroll
    for (int u = 0; u < 7; ++u)
        *(float4*)&buf[0][(u * 256 + tid) * 4] =
            *(const float4*)&src[(u * 256 + tid) * 4];
    __syncthreads();

    float acc = 0.0f;
    for (int c = 0; c < 7; ++c) {
        const int cb = c & 1;
        const bool have = (c + 1 < 7);
        float4 v[7];
        if (have) {
            const float* rp = src + (c + 1) * MCH2;
#pragma unroll
            for (int u = 0; u < 7; ++u)
                v[u] = *(const float4*)&rp[(u * 256 + tid) * 4];
        }
        if (tid == 0) {
            const float4* bp = (const float4*)buf[cb];   // 1792 float4
            float4 p0[8], p1[8];
#pragma unroll
            for (int u = 0; u < 8; ++u) p0[u] = bp[u];
            for (int gp = 0; gp < GRP; gp += 2) {
#pragma unroll
                for (int u = 0; u < 8; ++u) p1[u] = bp[(gp + 1) * 8 + u];
#pragma unroll
                for (int u = 0; u < 8; ++u) {
                    acc = __fadd_rn(acc, p0[u].x);
                    acc = __fadd_rn(acc, p0[u].y);
                    acc = __fadd_rn(acc, p0[u].z);
                    acc = __fadd_rn(acc, p0[u].w);
                }
                const int g2 = (gp + 2 < GRP) ? gp + 2 : 0;   // guarded wrap
#pragma unroll
                for (int u = 0; u < 8; ++u) p0[u] = bp[g2 * 8 + u];
#pragma unroll
                for (int u = 0; u < 8; ++u) {
                    acc = __fadd_rn(acc, p1[u].x);
                    acc = __fadd_rn(acc, p1[u].y);
                    acc = __fadd_rn(acc, p1[u].z);
                    acc = __fadd_rn(acc, p1[u].w);
                }
            }
        }
        if (have) {
#pragma unroll
            for (int u = 0; u < 7; ++u)
                *(float4*)&buf[cb ^ 1][(u * 256 + tid) * 4] = v[u];
        }
        __syncthreads();
    }
    if (tid == 0) mean_[blockIdx.x] = __fdiv_rn(acc, 50176.0f);
}

// ---------------------------------------------------------------------------
// Kernel 3a (hT path): var — per (t,b) chunk: f64 interior with the EXACT
// lane-strided partials + shuffle tree (bit-identical order); tb's run 4-way
// wave-parallel with coalesced loads; f32 join chain replayed serially.
// ---------------------------------------------------------------------------
extern "C" __global__ __launch_bounds__(256)
void var_hT(const float* __restrict__ hT, const float* __restrict__ mean_,
            float* __restrict__ inv_) {
    __shared__ float chunks[256];
    const int d    = blockIdx.x;
    const int tid  = threadIdx.x;
    const int wv   = tid >> 6;       // 0..3
    const int lane = tid & 63;
    const float mn = mean_[d];
    const float* col = hT + (size_t)d * M_;

    for (int tb = wv; tb < T_ * B_; tb += 4) {
        double part = 0.0;
        for (int n = lane; n < N_; n += 64) {
            const float hv = col[tb * N_ + n];
            const float t1 = __fsub_rn(hv, mn);
            const float sq = __fmul_rn(t1, t1);
            part += (double)sq;
        }
#pragma unroll
        for (int off = 32; off; off >>= 1) part += __shfl_down(part, off);
        if (lane == 0) chunks[tb] = (float)part;
    }
    __syncthreads();
    if (tid == 0) {
        float accf = 0.0f;
        for (int tb = 0; tb < T_ * B_; ++tb) accf = __fadd_rn(accf, chunks[tb]);
        const float var = __fdiv_rn(accf, 50176.0f);
        inv_[d] = __fdiv_rn(1.0f, __fsqrt_rn(__fadd_rn(var, 1e-5f)));
    }
}

// ---------------------------------------------------------------------------
// Fallback kernels (small workspace): read h[m][d] directly.
// ---------------------------------------------------------------------------
#define MCH  256
#define DCH  16
#define PADW 20
#define NCHK (M_/MCH)

extern "C" __global__ __launch_bounds__(256)
void mean_seq(const float* __restrict__ h, float* __restrict__ mean_) {
    __shared__ __align__(16) float buf[2][MCH][PADW];
    const int tid = threadIdx.x;
    const int d0  = blockIdx.x * DCH;
    {
        const float* rp = h + (size_t)tid * D_ + d0;
        *(float4*)&buf[0][tid][0]  = *(const float4*)(rp + 0);
        *(float4*)&buf[0][tid][4]  = *(const float4*)(rp + 4);
        *(float4*)&buf[0][tid][8]  = *(const float4*)(rp + 8);
        *(float4*)&buf[0][tid][12] = *(const float4*)(rp + 12);
    }
    __syncthreads();
    float acc = 0.0f;
    for (int c = 0; c < NCHK; ++c) {
        const int cb = c & 1;
        const bool have = (c + 1 < NCHK);
        float4 v0, v1, v2, v3;
        if (have) {
            const float* rp = h + ((size_t)(c + 1) * MCH + tid) * D_ + d0;
            v0 = *(const float4*)(rp + 0);
            v1 = *(const float4*)(rp + 4);
            v2 = *(const float4*)(rp + 8);
            v3 = *(const float4*)(rp + 12);
        }
        if (tid < DCH) {
#pragma unroll 16
            for (int m = 0; m < MCH; ++m)
                acc = __fadd_rn(acc, buf[cb][m][tid]);
        }
        if (have) {
            *(float4*)&buf[cb ^ 1][tid][0]  = v0;
            *(float4*)&buf[cb ^ 1][tid][4]  = v1;
            *(float4*)&buf[cb ^ 1][tid][8]  = v2;
            *(float4*)&buf[cb ^ 1][tid][12] = v3;
        }
        __syncthreads();
    }
    if (tid < DCH) mean_[d0 + tid] = __fdiv_rn(acc, 50176.0f);
}

extern "C" __global__ __launch_bounds__(64)
void var_seq(const float* __restrict__ h, const float* __restrict__ mean_,
             float* __restrict__ inv_) {
    const int d    = blockIdx.x;
    const int lane = threadIdx.x;
    const float mn = mean_[d];
    float accf = 0.0f;
    for (int tb = 0; tb < T_ * B_; ++tb) {
        double part = 0.0;
        for (int n = lane; n < N_; n += 64) {
            const float hv = h[((size_t)tb * N_ + n) * D_ + d];
            const float t1 = __fsub_rn(hv, mn);
            const float sq = __fmul_rn(t1, t1);
            part += (double)sq;
        }
#pragma unroll
        for (int off = 32; off; off >>= 1) part += __shfl_down(part, off);
        accf = __fadd_rn(accf, (float)part);
    }
    if (lane == 0) {
        const float var = __fdiv_rn(accf, 50176.0f);
        inv_[d] = __fdiv_rn(1.0f, __fsqrt_rn(__fadd_rn(var, 1e-5f)));
    }
}

// ---------------------------------------------------------------------------
// Kernel 3.5: pe table — identical f64 expressions as the inline path.
// ---------------------------------------------------------------------------
extern "C" __global__ __launch_bounds__(256)
void pe_build(float* __restrict__ pe_) {
    const int d = threadIdx.x;
    const int n = blockIdx.x;
    const double dv  = exp((double)(d & ~1) * (-9.210340371976184 / 256.0));
    const double arg = ((double)n * dv) * (256.0 / 196.0);
    pe_[(size_t)n * D_ + d] = (d & 1) ? (float)cos(arg) : (float)sin(arg);
}

// ---------------------------------------------------------------------------
// Kernel 4: BN-apply + LIF1 + tAPE + LIF2, exact numpy-f32 op order.
// ---------------------------------------------------------------------------
extern "C" __global__ __launch_bounds__(256)
void lif_final(float* __restrict__ out, const float* __restrict__ mean_,
               const float* __restrict__ inv_, const float* __restrict__ gamma,
               const float* __restrict__ beta, const float* __restrict__ pe_tab) {
    const int idx = blockIdx.x * 256 + threadIdx.x;   // (bn, d)
    const int d = idx & (D_ - 1);
    const int n = (idx >> 8) % N_;

    const float mn = mean_[d];
    const float iv = inv_[d];
    const float g  = gamma[d];
    const float b  = beta[d];

    float pe;
    if (pe_tab) {
        pe = pe_tab[(size_t)n * D_ + d];
    } else {
        const double dv  = exp((double)(d & ~1) * (-9.210340371976184 / 256.0));
        const double arg = ((double)n * dv) * (256.0 / 196.0);
        pe = (d & 1) ? (float)cos(arg) : (float)sin(arg);
    }

    float hv[4];
#pragma unroll
    for (int t = 0; t < T_; ++t) hv[t] = out[(size_t)t * SITES + idx];

    float v1 = 0.0f, v2 = 0.0f, s2v[4];
#pragma unroll
    for (int t = 0; t < T_; ++t) {
        const float t1 = __fsub_rn(hv[t], mn);
        const float u  = __fmul_rn(t1, iv);
        const float hb = __fadd_rn(__fmul_rn(u, g), b);
        v1 = __fadd_rn(v1, __fmul_rn(__fsub_rn(hb, v1), 0.5f));
        const float s1 = (v1 >= 0.5f) ? 1.0f : 0.0f;
        v1 = __fmul_rn(v1, __fsub_rn(1.0f, s1));
        const float y = __fadd_rn(s1, pe);
        v2 = __fadd_rn(v2, __fmul_rn(__fsub_rn(y, v2), 0.5f));
        const float s2 = (v2 >= 0.5f) ? 1.0f : 0.0f;
        v2 = __fmul_rn(v2, __fsub_rn(1.0f, s2));
        s2v[t] = s2;
    }
#pragma unroll
    for (int t = 0; t < T_; ++t) out[(size_t)t * SITES + idx] = s2v[t];
}

extern "C" void kernel_launch(void* const* d_in, const int* in_sizes, int n_in,
                              void* d_out, int out_size, void* d_ws, size_t ws_size,
                              hipStream_t stream) {
    const float* x     = (const float*)d_in[0];
    const float* w     = (const float*)d_in[1];
    const float* gamma = (const float*)d_in[2];
    const float* beta  = (const float*)d_in[3];
    float* out = (float*)d_out;

    float* mean_ = (float*)d_ws;              // 256
    float* inv_  = mean_ + D_;                // 256
    float* pe_   = inv_  + D_;                // 196*256
    float* hT_   = pe_   + (size_t)N_ * D_;   // 50176*256 (51.4 MB)

    const size_t need_pe = (size_t)(2 * D_ + N_ * D_) * sizeof(float);
    const size_t need_hT = need_pe + (size_t)M_ * D_ * sizeof(float);
    const bool use_pe = ws_size >= need_pe;
    const bool use_hT = ws_size >= need_hT;

    gemm_f32emu<<<MBLKS * NBLKS, 256, 0, stream>>>(x, w, out,
                                                   use_hT ? hT_ : nullptr);
    if (use_hT) {
        mean_hT<<<D_, 256, 0, stream>>>(hT_, mean_);
        var_hT<<<D_, 256, 0, stream>>>(hT_, mean_, inv_);
    } else {
        mean_seq<<<16, 256, 0, stream>>>(out, mean_);
        var_seq<<<D_, 64, 0, stream>>>(out, mean_, inv_);
    }
    if (use_pe) pe_build<<<N_, 256, 0, stream>>>(pe_);
    lif_final<<<SITES / 256, 256, 0, stream>>>(out, mean_, inv_, gamma, beta,
                                               use_pe ? pe_ : nullptr);
}